// Round 1
// baseline (86.423 us; speedup 1.0000x reference)
//
#include <hip/hip_runtime.h>

// 3-qubit, 2-layer RY/CNOT circuit -> <Z_i> per batch element.
// State = 8 real floats in registers. Index s = q0*4 + q1*2 + q2.
// Memory-bound: 33.5 MB read (x as float4) + 25.2 MB write (out via LDS
// transpose for fully coalesced stride-1 stores).

__global__ __launch_bounds__(256) void qfl_kernel(
    const float4* __restrict__ x, const float* __restrict__ w,
    float* __restrict__ out, int n)
{
    __shared__ float swc[6], sws[6];   // per-layer/wire weight cos/sin (batch-uniform)
    __shared__ float sout[768];        // 256 elements x 3 outputs, staged for coalesced store
    const int tid = threadIdx.x;
    const long long b = (long long)blockIdx.x * 256 + tid;

    // Weights are uniform across the batch: compute their sincos once per block.
    if (tid < 6) {
        float t = 0.5f * w[tid];
        sws[tid] = __sinf(t);
        swc[tid] = __cosf(t);
    }
    __syncthreads();

    float4 xv = (b < (long long)n) ? x[b] : make_float4(0.f, 0.f, 0.f, 0.f);

    // Angle encoding: RY(x_i * PI) on wire i, applied to |0> per wire ->
    // state is the tensor product (a0,a1) x (b0,b1) x (c0,c1).
    const float HPI = 0.5f * 3.14159f;  // matches reference's PI literal
    float a0, a1, b0, b1, c0, c1;
    __sincosf(xv.x * HPI, &a1, &a0);
    __sincosf(xv.y * HPI, &b1, &b0);
    __sincosf(xv.z * HPI, &c1, &c0);

    float st[8];
    st[0] = a0 * b0 * c0; st[1] = a0 * b0 * c1;
    st[2] = a0 * b1 * c0; st[3] = a0 * b1 * c1;
    st[4] = a1 * b0 * c0; st[5] = a1 * b0 * c1;
    st[6] = a1 * b1 * c0; st[7] = a1 * b1 * c1;

    #pragma unroll
    for (int l = 0; l < 2; ++l) {
        {   // RY on wire 0: pairs (k, k+4)
            float c = swc[l * 3 + 0], s = sws[l * 3 + 0];
            #pragma unroll
            for (int k = 0; k < 4; ++k) {
                float u = st[k], v = st[k + 4];
                st[k] = c * u - s * v; st[k + 4] = s * u + c * v;
            }
        }
        {   // RY on wire 1: pairs (0,2),(1,3),(4,6),(5,7)
            float c = swc[l * 3 + 1], s = sws[l * 3 + 1];
            #pragma unroll
            for (int k = 0; k < 2; ++k) {
                float u = st[k],     v = st[k + 2];
                st[k]     = c * u  - s * v;  st[k + 2] = s * u  + c * v;
                float u2 = st[k + 4], v2 = st[k + 6];
                st[k + 4] = c * u2 - s * v2; st[k + 6] = s * u2 + c * v2;
            }
        }
        {   // RY on wire 2: pairs (even, even+1)
            float c = swc[l * 3 + 2], s = sws[l * 3 + 2];
            #pragma unroll
            for (int k = 0; k < 8; k += 2) {
                float u = st[k], v = st[k + 1];
                st[k] = c * u - s * v; st[k + 1] = s * u + c * v;
            }
        }
        // CNOT(ctrl=0, tgt=1): where q0=1 flip q1 -> swap 4<->6, 5<->7
        { float t = st[4]; st[4] = st[6]; st[6] = t;
          t = st[5]; st[5] = st[7]; st[7] = t; }
        // CNOT(ctrl=1, tgt=2): where q1=1 flip q2 -> swap 2<->3, 6<->7
        { float t = st[2]; st[2] = st[3]; st[3] = t;
          t = st[6]; st[6] = st[7]; st[7] = t; }
    }

    // <Z_i> = sum_s p_s * (1 - 2*bit_i(s)), bit0 = s>>2, bit1 = s>>1, bit2 = s
    float p[8];
    #pragma unroll
    for (int k = 0; k < 8; ++k) p[k] = st[k] * st[k];
    float o0 = (p[0] + p[1] + p[2] + p[3]) - (p[4] + p[5] + p[6] + p[7]);
    float o1 = (p[0] + p[1] + p[4] + p[5]) - (p[2] + p[3] + p[6] + p[7]);
    float o2 = (p[0] + p[2] + p[4] + p[6]) - (p[1] + p[3] + p[5] + p[7]);

    // Stage in LDS (stride-3 writes: 3 coprime with 32 banks -> conflict-free),
    // then 3 fully coalesced stride-1 global stores per lane.
    sout[3 * tid + 0] = o0;
    sout[3 * tid + 1] = o1;
    sout[3 * tid + 2] = o2;
    __syncthreads();

    const long long base  = (long long)blockIdx.x * 768;
    const long long total = (long long)n * 3;
    #pragma unroll
    for (int k = 0; k < 3; ++k) {
        long long idx = base + k * 256 + tid;
        if (idx < total) out[idx] = sout[k * 256 + tid];
    }
}

extern "C" void kernel_launch(void* const* d_in, const int* in_sizes, int n_in,
                              void* d_out, int out_size, void* d_ws, size_t ws_size,
                              hipStream_t stream) {
    const float4* x = (const float4*)d_in[0];   // (B, 4) float32, row = one float4
    const float*  w = (const float*)d_in[1];    // (2, 3) float32
    float* out = (float*)d_out;                 // (B, 3) float32
    int n = in_sizes[0] / 4;
    int blocks = (n + 255) / 256;
    qfl_kernel<<<blocks, 256, 0, stream>>>(x, w, out, n);
}